// Round 3
// baseline (15554.861 us; speedup 1.0000x reference)
//
#include <hip/hip_runtime.h>

#define T_LEN 512
#define BATCH 64
#define HID   512
#define EMB   512
#define NWG   256
#define TPB   512
#define RING_SLOT (HID * BATCH)   // 32768 floats per slot, layout [j][b]

// ---- grid barrier state (lives in d_ws, zeroed by init kernel) ----
// Monotonic counters (never reset): leaf[g] gets 16 incs/slot, root gets 16.
// Release: root winner stores epoch; EVERYONE ELSE polls epoch directly
// (flat release — the old gep tier cost ~2 extra L3 hops per step).
struct GBar {
  int leaf[16 * 32];   // arrival counter per group, one cacheline apart
  int root; int pad1[31];
  int epoch; int pad2[31];
  int gep[16 * 32];    // unused now; kept so ws layout/zeroing is unchanged
};

__global__ void init_ws_kernel(int* ws, int n) {
  int stride = gridDim.x * blockDim.x;
  for (int i = blockIdx.x * blockDim.x + threadIdx.x; i < n; i += stride) ws[i] = 0;
}

__device__ __forceinline__ float sigm(float x)      { return 1.f / (1.f + __expf(-x)); }
// saturation-safe tanh: x->+inf => 1, x->-inf => -1, no inf/inf NaN
__device__ __forceinline__ float tanh_fast(float x) { return 1.f - 2.f / (__expf(2.f * x) + 1.f); }

// coherent (device-scope, cache-bypassing) scalar store — no fences needed
__device__ __forceinline__ void cstore(float* p, float v) {
  __hip_atomic_store(p, v, __ATOMIC_RELAXED, __HIP_MEMORY_SCOPE_AGENT);
}

// butterfly sum across the 4 lanes of a quad (rg = lane&3) via DPP quad_perm.
// 0xB1 = quad_perm:[1,0,3,2] (xor 1), 0x4E = quad_perm:[2,3,0,1] (xor 2).
// All lanes end with the full 4-lane sum; stays on the VALU pipe (no LDS).
__device__ __forceinline__ float qsum(float v) {
  int t = __builtin_amdgcn_update_dpp(0, __float_as_int(v), 0xB1, 0xF, 0xF, false);
  v += __int_as_float(t);
  t = __builtin_amdgcn_update_dpp(0, __float_as_int(v), 0x4E, 0xF, 0xF, false);
  v += __int_as_float(t);
  return v;
}

// ---- coherent 16B load, fire-and-forget (NO waitcnt): sc0 sc1 bypass L1/L2
// so no stale lines are possible; completion enforced by counted WAIT_VM.
template <int I, int N>
struct IssueQ {
  static __device__ __forceinline__ void go(float4* dst, const float* p) {
    asm volatile("global_load_dwordx4 %0, %1, off offset:%2 sc0 sc1"
                 : "=v"(dst[I]) : "v"(p), "i"(I * 256));
    IssueQ<I + 1, N>::go(dst, p);
  }
};
template <int N>
struct IssueQ<N, N> {
  static __device__ __forceinline__ void go(float4*, const float*) {}
};

// s_waitcnt vmcnt(n) as a hard scheduling fence. asm-volatile statements are
// mutually ordered (the wait stays after the IssueQ loads); the
// sched_barrier(0) pair pins ALL other instructions (incl. the consuming
// FMAs) on their side of the wait. vmcnt retires FIFO: vmcnt(n) guarantees
// the oldest (issued-n) loads have landed. Any compiler-issued VMEM ops
// (cstore/out/atomics) precede our loads in program order, so they only make
// the counted wait STRONGER, never weaker.
#define WAIT_VM(n) do {                                     \
    __builtin_amdgcn_sched_barrier(0);                      \
    asm volatile("s_waitcnt vmcnt(" #n ")" ::: "memory");   \
    __builtin_amdgcn_sched_barrier(0);                      \
  } while (0)

// acc (scalar) += dot(xv, wv)
#define DOT_ACC(a, xv, wv) \
  a = fmaf((xv).w, (wv).w, fmaf((xv).z, (wv).z, fmaf((xv).y, (wv).y, fmaf((xv).x, (wv).x, (a)))))
// acc (float4 over b) += s * v (float4 over b)
#define AXPY4(acc, s, v) do { \
  (acc).x = fmaf((s), (v).x, (acc).x); \
  (acc).y = fmaf((s), (v).y, (acc).y); \
  (acc).z = fmaf((s), (v).z, (acc).z); \
  (acc).w = fmaf((s), (v).w, (acc).w); } while (0)

// NOTE __launch_bounds__(TPB, 1): with 96 KB LDS/block only 1 block/CU can be
// resident (and grid == 256 == #CUs), so the old ",2" bound bought nothing —
// it only capped the allocator at 128 VGPRs and spilled the ring pipeline to
// scratch (round 2: WRITE_SIZE 141 MB -> 23.9 GB). At 1 block/CU the budget
// is 256 VGPRs (2 waves/SIMD); the ring path needs ~180.
__global__ __launch_bounds__(TPB, 1) void lstm_pipe(
    const int* __restrict__ src, const int* __restrict__ sen_len,
    const float* __restrict__ emb,
    const float* __restrict__ Wih0, const float* __restrict__ Whh0,
    const float* __restrict__ bih0, const float* __restrict__ bhh0,
    const float* __restrict__ Wih1, const float* __restrict__ Whh1,
    const float* __restrict__ bih1, const float* __restrict__ bhh1,
    float* __restrict__ out,
    int* __restrict__ barp, float* __restrict__ h0ring, float* __restrict__ h1ring)
{
  extern __shared__ char smem_raw[];
  float4* WlV  = (float4*)smem_raw;            // 4096 float4 = 64 KB: [kc][16 slots]
  float*  part = (float*)(smem_raw + 65536);   // 8192 floats = 32 KB: [kh][row][b]
  GBar* bar = (GBar*)barp;

  const int wg    = blockIdx.x;
  const int layer = wg >> 7;    // 0: WGs 0..127 (layer0 @ t=s), 1: WGs 128..255 (layer1 @ t=s-1)
  const int w     = wg & 127;   // owns hidden units j in [4w, 4w+4)
  const int tid   = threadIdx.x;
  const int kh    = tid >> 6;   // 0..7  K-segment of 128
  const int lane  = tid & 63;
  const int bg    = lane >> 2;  // 0..15 batch-group (4 batches)
  const int rg    = lane & 3;   // 0..3  ring: K-quarter of 32 | emb: j within WG
  const int b0    = bg << 2;    // batches b0..b0+3 (contiguous)
  const int k0    = kh << 7;    // K range [k0, k0+128)

  const float* Wih = layer ? Wih1 : Wih0;
  const float* Whh = layer ? Whh1 : Whh0;

  // Stage 16 rows x 1024 K of fused [Wih | Whh] weights into LDS, [kc][16] float4.
  // Row-slot swizzle: slot = (rowl + 2*((kc>>3)&3)) & 15.  In ring mode the 4
  // rg lanes read kc's 8 apart ((kc>>3)&3 == rg) => banks spread 0/8/16/24;
  // in emb mode rg is consecutive in the slot => 4 adjacent 16B slots. Both
  // conflict-free; bijective per kc.
  for (int idx = tid; idx < 4096; idx += TPB) {
    int rowl = idx & 15;          // q*4 + rjj
    int kc   = idx >> 4;          // 0..255
    int q = rowl >> 2, rjj = rowl & 3;
    int grow = q * HID + (w << 2) + rjj;   // global gate row
    int k4 = kc << 2;
    float4 v;
    if (k4 < EMB) v = *(const float4*)(Wih + (size_t)grow * EMB + k4);
    else          v = *(const float4*)(Whh + (size_t)grow * HID + (k4 - EMB));
    int slot = (rowl + 2 * ((kc >> 3) & 3)) & 15;
    WlV[kc * 16 + slot] = v;
  }

  // Per-thread swizzled weight byte-offset table (loop-invariant over all
  // steps; statically indexed everywhere -> stays in VGPRs).
  const bool embmode = (layer == 0) && (kh < 4);
  int toff[16];
  {
    const int add = embmode ? rg : (rg << 1);
#pragma unroll
    for (int i = 0; i < 16; ++i) toff[i] = ((i + add) & 15) << 4;
  }
  const char* wb_ring = (const char*)smem_raw + (size_t)((kh << 5) + (rg << 3)) * 256; // kc_base*256
  const char* wb_emb  = (const char*)smem_raw + (size_t)(kh << 13);                    // kh*8192

  // Activation-phase identity: threads 0..255 own cell (jj, b); c lives here.
  const int p_b  = tid & 63;
  const int p_jj = (tid >> 6) & 3;
  const int p_jg = (w << 2) + p_jj;
  float bias4[4] = {0.f, 0.f, 0.f, 0.f};
  float c = 0.f;
  int   slen = -2;
  if (tid < 256) {
#pragma unroll
    for (int q = 0; q < 4; ++q) {
      int r = q * HID + p_jg;
      bias4[q] = layer ? (bih1[r] + bhh1[r]) : (bih0[r] + bhh0[r]);
    }
    slen = sen_len[p_b];
  }
  __syncthreads();

  for (int s = 0; s <= T_LEN; ++s) {
    const bool active = (layer == 0) ? (s < T_LEN) : (s >= 1);
    if (active) {
      const int t = (layer == 0) ? s : (s - 1);

      if (embmode) {
        // ---- embedding-gather mode: read-only data, normal cached loads ----
        float4 acc[4];
#pragma unroll
        for (int q = 0; q < 4; ++q) acc[q] = make_float4(0.f, 0.f, 0.f, 0.f);
        const int* st = src + t * BATCH + b0;
        const float* e0 = emb + (size_t)st[0] * EMB;
        const float* e1 = emb + (size_t)st[1] * EMB;
        const float* e2 = emb + (size_t)st[2] * EMB;
        const float* e3 = emb + (size_t)st[3] * EMB;
#pragma unroll
        for (int kk = 0; kk < 128; kk += 4) {
          const int sw = (kk >> 5) & 3;           // compile-time (full unroll)
          const int k  = k0 + kk;
          float4 x0 = *(const float4*)(e0 + k);
          float4 x1 = *(const float4*)(e1 + k);
          float4 x2 = *(const float4*)(e2 + k);
          float4 x3 = *(const float4*)(e3 + k);
#pragma unroll
          for (int q = 0; q < 4; ++q) {
            float4 wq = *(const float4*)(wb_emb + kk * 64 + toff[((q << 2) + 2 * sw) & 15]);
            DOT_ACC(acc[q].x, x0, wq);
            DOT_ACC(acc[q].y, x1, wq);
            DOT_ACC(acc[q].z, x2, wq);
            DOT_ACC(acc[q].w, x3, wq);
          }
        }
        // partials: part[kh][row][b], row = q*4+rg
#pragma unroll
        for (int q = 0; q < 4; ++q)
          *(float4*)(part + (kh << 10) + (((q << 2) + rg) << 6) + b0) = acc[q];
      } else {
        // ---- transposed-ring mode: each quad lane owns a disjoint K-quarter
        // of 32 k's and accumulates ALL 16 gate-rows for its 4 batches.
        // 32 coherent loads/thread (was 128 with 4x quad redundancy).
        // Bounded 2-deep pipeline: xa[8]/xb[8] double buffer (64 VGPRs in
        // flight max), 4 groups of 8 loads (2 kc each), waits vmcnt(8,8,8,0).
        // Per-group FMA cover (512 fmaf/thread) >= coherent-load latency.
        const float* xT;
        if (layer == 0) {
          xT = h0ring + ((s + 1) & 1) * RING_SLOT + (k0 - EMB) * BATCH;
        } else if (kh < 4) {
          xT = h0ring + ((s - 1) & 1) * RING_SLOT + k0 * BATCH;
        } else {
          xT = h1ring + ((s - 1) & 1) * RING_SLOT + (k0 - EMB) * BATCH;
        }
        const float* p = xT + (rg << 5) * BATCH + b0;  // this lane's K-quarter panel

        float4 acc[16];
#pragma unroll
        for (int m = 0; m < 16; ++m) acc[m] = make_float4(0.f, 0.f, 0.f, 0.f);

        float4 xa[8], xb[8];
        IssueQ<0, 8>::go(xa, p);                       // k 0..7 of this lane in flight

#define RING_GRP(G, CUR, NXT, WN, DO_ISSUE)                                   \
        do {                                                                  \
          if (DO_ISSUE) IssueQ<0, 8>::go(NXT, p + ((G) + 1) * 8 * BATCH);     \
          WAIT_VM(WN);                                                        \
          _Pragma("unroll")                                                   \
          for (int cc = 0; cc < 2; ++cc) {                                    \
            _Pragma("unroll")                                                 \
            for (int m = 0; m < 16; ++m) {                                    \
              float4 wq = *(const float4*)(wb_ring + ((G) * 2 + cc) * 256 + toff[m]); \
              AXPY4(acc[m], wq.x, (CUR)[cc * 4 + 0]);                         \
              AXPY4(acc[m], wq.y, (CUR)[cc * 4 + 1]);                         \
              AXPY4(acc[m], wq.z, (CUR)[cc * 4 + 2]);                         \
              AXPY4(acc[m], wq.w, (CUR)[cc * 4 + 3]);                         \
            }                                                                 \
          }                                                                   \
        } while (0)

        RING_GRP(0, xa, xb, 8, true);
        RING_GRP(1, xb, xa, 8, true);
        RING_GRP(2, xa, xb, 8, true);
        RING_GRP(3, xb, xa, 0, false);
#undef RING_GRP

        // pre-reduce the 4 K-quarters across the quad (DPP butterfly), then
        // lane rg==0 writes the full 16-row partial: part[kh][m][b0..b0+3].
#pragma unroll
        for (int m = 0; m < 16; ++m) {
          acc[m].x = qsum(acc[m].x);
          acc[m].y = qsum(acc[m].y);
          acc[m].z = qsum(acc[m].z);
          acc[m].w = qsum(acc[m].w);
        }
        if (rg == 0) {
#pragma unroll
          for (int m = 0; m < 16; ++m)
            *(float4*)(part + (kh << 10) + (m << 6) + b0) = acc[m];
        }
      }
    }

    __syncthreads();  // partials visible

    if (active && tid < 256) {
      float g4[4];
#pragma unroll
      for (int q = 0; q < 4; ++q) {
        float a = bias4[q];
        const int base = (((q << 2) + p_jj) << 6) + p_b;
#pragma unroll
        for (int kk = 0; kk < 8; ++kk) a += part[(kk << 10) + base];
        g4[q] = a;
      }
      float ig = sigm(g4[0]), fg = sigm(g4[1]), gg = tanh_fast(g4[2]), og = sigm(g4[3]);
      c = fmaf(fg, c, ig * gg);
      float h = og * tanh_fast(c);
      float* ring = (layer == 0 ? h0ring : h1ring) + (s & 1) * RING_SLOT;
      cstore(ring + p_jg * BATCH + p_b, h);   // coherent store [j][b], coalesced
      if (layer == 1) {
        const int t = s - 1;
        if (t == slen - 1) out[p_b * HID + p_jg] = h;
      }
    }

    // ---- hierarchical arrive, FLAT release, all-RELAXED, monotonic ----
    // __syncthreads() drains vmcnt(0): every coherent h-store is committed at
    // the IF coherence point before tid0's arrival increment. Consumers read
    // ring data with coherent (sc0 sc1) loads after observing the release.
    __syncthreads();
    if (tid == 0) {
      const int target = s + 1;
      int* leafp = &bar->leaf[(wg >> 4) * 32];
      int prev = __hip_atomic_fetch_add(leafp, 1, __ATOMIC_RELAXED, __HIP_MEMORY_SCOPE_AGENT);
      bool winner = false;
      if ((prev & 15) == 15) {   // 16th arrival of this slot in this group
        int r = __hip_atomic_fetch_add(&bar->root, 1, __ATOMIC_RELAXED, __HIP_MEMORY_SCOPE_AGENT);
        if ((r & 15) == 15) {    // 16th group — release everyone
          __hip_atomic_store(&bar->epoch, target, __ATOMIC_RELAXED, __HIP_MEMORY_SCOPE_AGENT);
          winner = true;
        }
      }
      if (!winner) {
        while (__hip_atomic_load(&bar->epoch, __ATOMIC_RELAXED, __HIP_MEMORY_SCOPE_AGENT) < target)
          __builtin_amdgcn_s_sleep(1);
      }
    }
    __syncthreads();
  }
}

extern "C" void kernel_launch(void* const* d_in, const int* in_sizes, int n_in,
                              void* d_out, int out_size, void* d_ws, size_t ws_size,
                              hipStream_t stream) {
  const int*   src  = (const int*)d_in[0];
  const int*   slen = (const int*)d_in[1];
  const float* emb  = (const float*)d_in[2];
  const float* Wih0 = (const float*)d_in[3];
  const float* Whh0 = (const float*)d_in[4];
  const float* bih0 = (const float*)d_in[5];
  const float* bhh0 = (const float*)d_in[6];
  const float* Wih1 = (const float*)d_in[7];
  const float* Whh1 = (const float*)d_in[8];
  const float* bih1 = (const float*)d_in[9];
  const float* bhh1 = (const float*)d_in[10];
  float* out = (float*)d_out;

  int*   bar    = (int*)d_ws;
  float* h0ring = (float*)((char*)d_ws + 8192);
  float* h1ring = h0ring + 2 * RING_SLOT;

  // zero barrier state + all 4 ring slots (ws is poisoned 0xAA before every launch)
  int zero_ints = (8192 + 4 * RING_SLOT * 4) / 4;
  hipLaunchKernelGGL(init_ws_kernel, dim3(64), dim3(256), 0, stream, (int*)d_ws, zero_ints);

  (void)hipFuncSetAttribute((const void*)lstm_pipe,
                            hipFuncAttributeMaxDynamicSharedMemorySize, 98304);

  hipLaunchKernelGGL(lstm_pipe, dim3(NWG), dim3(TPB), 98304, stream,
                     src, slen, emb, Wih0, Whh0, bih0, bhh0, Wih1, Whh1, bih1, bhh1,
                     out, bar, h0ring, h1ring);
}

// Round 4
// 15487.593 us; speedup vs baseline: 1.0043x; 1.0043x over previous
//
#include <hip/hip_runtime.h>

#define T_LEN 512
#define BATCH 64
#define HID   512
#define EMB   512
#define NWG   256
#define TPB   512
#define RING_SLOT (HID * BATCH)   // 32768 floats per slot, layout [j][b]

// ---- grid barrier state (lives in d_ws, zeroed by init kernel) ----
// Monotonic counters (never reset): leaf[g] gets 16 incs/slot, root gets 16.
// Release: root winner stores epoch; EVERYONE ELSE polls epoch directly
// (flat release — the old gep tier cost ~2 extra L3 hops per step).
struct GBar {
  int leaf[16 * 32];   // arrival counter per group, one cacheline apart
  int root; int pad1[31];
  int epoch; int pad2[31];
  int gep[16 * 32];    // unused now; kept so ws layout/zeroing is unchanged
};

__global__ void init_ws_kernel(int* ws, int n) {
  int stride = gridDim.x * blockDim.x;
  for (int i = blockIdx.x * blockDim.x + threadIdx.x; i < n; i += stride) ws[i] = 0;
}

__device__ __forceinline__ float sigm(float x)      { return 1.f / (1.f + __expf(-x)); }
// saturation-safe tanh: x->+inf => 1, x->-inf => -1, no inf/inf NaN
__device__ __forceinline__ float tanh_fast(float x) { return 1.f - 2.f / (__expf(2.f * x) + 1.f); }

// coherent (device-scope, cache-bypassing) scalar store — no fences needed
__device__ __forceinline__ void cstore(float* p, float v) {
  __hip_atomic_store(p, v, __ATOMIC_RELAXED, __HIP_MEMORY_SCOPE_AGENT);
}

// butterfly sum across the 4 lanes of a quad (rg = lane&3) via DPP quad_perm.
// 0xB1 = quad_perm:[1,0,3,2] (xor 1), 0x4E = quad_perm:[2,3,0,1] (xor 2).
// All lanes end with the full 4-lane sum; stays on the VALU pipe (no LDS).
__device__ __forceinline__ float qsum(float v) {
  int t = __builtin_amdgcn_update_dpp(0, __float_as_int(v), 0xB1, 0xF, 0xF, false);
  v += __int_as_float(t);
  t = __builtin_amdgcn_update_dpp(0, __float_as_int(v), 0x4E, 0xF, 0xF, false);
  v += __int_as_float(t);
  return v;
}

// ---- coherent 16B load, fire-and-forget (NO waitcnt): sc0 sc1 bypass L1/L2
// so no stale lines are possible; completion enforced by counted WAIT_VM.
template <int I, int N>
struct IssueQ {
  static __device__ __forceinline__ void go(float4* dst, const float* p) {
    asm volatile("global_load_dwordx4 %0, %1, off offset:%2 sc0 sc1"
                 : "=v"(dst[I]) : "v"(p), "i"(I * 256));
    IssueQ<I + 1, N>::go(dst, p);
  }
};
template <int N>
struct IssueQ<N, N> {
  static __device__ __forceinline__ void go(float4*, const float*) {}
};

// s_waitcnt vmcnt(n) as a hard scheduling fence. asm-volatile statements are
// mutually ordered (the wait stays after the IssueQ loads); the
// sched_barrier(0) pair pins ALL other instructions (incl. the consuming
// FMAs) on their side of the wait. vmcnt retires FIFO: vmcnt(n) guarantees
// the oldest (issued-n) loads have landed. Any compiler-issued VMEM ops
// (cstore/out/atomics) precede our loads in program order, so they only make
// the counted wait STRONGER, never weaker.
#define WAIT_VM(n) do {                                     \
    __builtin_amdgcn_sched_barrier(0);                      \
    asm volatile("s_waitcnt vmcnt(" #n ")" ::: "memory");   \
    __builtin_amdgcn_sched_barrier(0);                      \
  } while (0)

// acc (scalar) += dot(xv, wv)
#define DOT_ACC(a, xv, wv) \
  a = fmaf((xv).w, (wv).w, fmaf((xv).z, (wv).z, fmaf((xv).y, (wv).y, fmaf((xv).x, (wv).x, (a)))))
// acc (float4 over b) += s * v (float4 over b)
#define AXPY4(acc, s, v) do { \
  (acc).x = fmaf((s), (v).x, (acc).x); \
  (acc).y = fmaf((s), (v).y, (acc).y); \
  (acc).z = fmaf((s), (v).z, (acc).z); \
  (acc).w = fmaf((s), (v).w, (acc).w); } while (0)

// REGISTER BUDGET NOTE (rounds 2-3 post-mortem): with extern __shared__ the
// static LDS is 0, so the backend's occupancy heuristic can't see that 96 KB
// dynamic LDS limits us to 1 block/CU (2 waves/SIMD). It targeted 4 waves/EU
// => a 128-VGPR budget => ~96 VGPRs of pipeline state spilled to scratch
// (WRITE_SIZE 141 MB -> 23.9 GB, dur 3x). launch_bounds' 2nd arg only sets
// the MIN waves/EU and cannot lower that target; amdgpu_waves_per_eu(min,max)
// sets the MAX, which the heuristic honors. max=2 == what the hardware gives
// us anyway, so this costs nothing and raises the VGPR budget to 256.
__global__ __launch_bounds__(TPB, 1) __attribute__((amdgpu_waves_per_eu(1, 2)))
void lstm_pipe(
    const int* __restrict__ src, const int* __restrict__ sen_len,
    const float* __restrict__ emb,
    const float* __restrict__ Wih0, const float* __restrict__ Whh0,
    const float* __restrict__ bih0, const float* __restrict__ bhh0,
    const float* __restrict__ Wih1, const float* __restrict__ Whh1,
    const float* __restrict__ bih1, const float* __restrict__ bhh1,
    float* __restrict__ out,
    int* __restrict__ barp, float* __restrict__ h0ring, float* __restrict__ h1ring)
{
  extern __shared__ char smem_raw[];
  float4* WlV  = (float4*)smem_raw;            // 4096 float4 = 64 KB: [kc][16 slots]
  float*  part = (float*)(smem_raw + 65536);   // 8192 floats = 32 KB: [kh][row][b]
  GBar* bar = (GBar*)barp;

  const int wg    = blockIdx.x;
  const int layer = wg >> 7;    // 0: WGs 0..127 (layer0 @ t=s), 1: WGs 128..255 (layer1 @ t=s-1)
  const int w     = wg & 127;   // owns hidden units j in [4w, 4w+4)
  const int tid   = threadIdx.x;
  const int kh    = tid >> 6;   // 0..7  K-segment of 128
  const int lane  = tid & 63;
  const int bg    = lane >> 2;  // 0..15 batch-group (4 batches)
  const int rg    = lane & 3;   // 0..3  ring: K-quarter of 32 | emb: j within WG
  const int b0    = bg << 2;    // batches b0..b0+3 (contiguous)
  const int k0    = kh << 7;    // K range [k0, k0+128)

  const float* Wih = layer ? Wih1 : Wih0;
  const float* Whh = layer ? Whh1 : Whh0;

  // Stage 16 rows x 1024 K of fused [Wih | Whh] weights into LDS, [kc][16] float4.
  // Row-slot swizzle: slot = (rowl + 2*((kc>>3)&3)) & 15.  In ring mode the 4
  // rg lanes read kc's 8 apart ((kc>>3)&3 == rg) => banks spread 0/8/16/24;
  // in emb mode rg is consecutive in the slot => 4 adjacent 16B slots. Both
  // conflict-free; bijective per kc.
  for (int idx = tid; idx < 4096; idx += TPB) {
    int rowl = idx & 15;          // q*4 + rjj
    int kc   = idx >> 4;          // 0..255
    int q = rowl >> 2, rjj = rowl & 3;
    int grow = q * HID + (w << 2) + rjj;   // global gate row
    int k4 = kc << 2;
    float4 v;
    if (k4 < EMB) v = *(const float4*)(Wih + (size_t)grow * EMB + k4);
    else          v = *(const float4*)(Whh + (size_t)grow * HID + (k4 - EMB));
    int slot = (rowl + 2 * ((kc >> 3) & 3)) & 15;
    WlV[kc * 16 + slot] = v;
  }

  // Per-thread swizzled weight byte-offset table (loop-invariant over all
  // steps; statically indexed everywhere -> stays in VGPRs).
  const bool embmode = (layer == 0) && (kh < 4);
  int toff[16];
  {
    const int add = embmode ? rg : (rg << 1);
#pragma unroll
    for (int i = 0; i < 16; ++i) toff[i] = ((i + add) & 15) << 4;
  }
  const char* wb_ring = (const char*)smem_raw + (size_t)((kh << 5) + (rg << 3)) * 256; // kc_base*256
  const char* wb_emb  = (const char*)smem_raw + (size_t)(kh << 13);                    // kh*8192

  // Activation-phase identity: threads 0..255 own cell (jj, b); c lives here.
  const int p_b  = tid & 63;
  const int p_jj = (tid >> 6) & 3;
  const int p_jg = (w << 2) + p_jj;
  float bias4[4] = {0.f, 0.f, 0.f, 0.f};
  float c = 0.f;
  int   slen = -2;
  if (tid < 256) {
#pragma unroll
    for (int q = 0; q < 4; ++q) {
      int r = q * HID + p_jg;
      bias4[q] = layer ? (bih1[r] + bhh1[r]) : (bih0[r] + bhh0[r]);
    }
    slen = sen_len[p_b];
  }
  __syncthreads();

  for (int s = 0; s <= T_LEN; ++s) {
    const bool active = (layer == 0) ? (s < T_LEN) : (s >= 1);
    if (active) {
      const int t = (layer == 0) ? s : (s - 1);

      if (embmode) {
        // ---- embedding-gather mode: read-only data, normal cached loads ----
        float4 acc[4];
#pragma unroll
        for (int q = 0; q < 4; ++q) acc[q] = make_float4(0.f, 0.f, 0.f, 0.f);
        const int* st = src + t * BATCH + b0;
        const float* e0 = emb + (size_t)st[0] * EMB;
        const float* e1 = emb + (size_t)st[1] * EMB;
        const float* e2 = emb + (size_t)st[2] * EMB;
        const float* e3 = emb + (size_t)st[3] * EMB;
#pragma unroll
        for (int kk = 0; kk < 128; kk += 4) {
          const int sw = (kk >> 5) & 3;           // compile-time (full unroll)
          const int k  = k0 + kk;
          float4 x0 = *(const float4*)(e0 + k);
          float4 x1 = *(const float4*)(e1 + k);
          float4 x2 = *(const float4*)(e2 + k);
          float4 x3 = *(const float4*)(e3 + k);
#pragma unroll
          for (int q = 0; q < 4; ++q) {
            float4 wq = *(const float4*)(wb_emb + kk * 64 + toff[((q << 2) + 2 * sw) & 15]);
            DOT_ACC(acc[q].x, x0, wq);
            DOT_ACC(acc[q].y, x1, wq);
            DOT_ACC(acc[q].z, x2, wq);
            DOT_ACC(acc[q].w, x3, wq);
          }
        }
        // partials: part[kh][row][b], row = q*4+rg
#pragma unroll
        for (int q = 0; q < 4; ++q)
          *(float4*)(part + (kh << 10) + (((q << 2) + rg) << 6) + b0) = acc[q];
      } else {
        // ---- transposed-ring mode: each quad lane owns a disjoint K-quarter
        // of 32 k's and accumulates ALL 16 gate-rows for its 4 batches.
        // 32 coherent loads/thread (was 128 with 4x quad redundancy).
        // Bounded 2-deep pipeline: xa[8]/xb[8] double buffer (64 VGPRs in
        // flight max), 4 groups of 8 loads (2 kc each), waits vmcnt(8,8,8,0).
        // Per-group FMA cover (512 fmaf/thread) >= coherent-load latency.
        const float* xT;
        if (layer == 0) {
          xT = h0ring + ((s + 1) & 1) * RING_SLOT + (k0 - EMB) * BATCH;
        } else if (kh < 4) {
          xT = h0ring + ((s - 1) & 1) * RING_SLOT + k0 * BATCH;
        } else {
          xT = h1ring + ((s - 1) & 1) * RING_SLOT + (k0 - EMB) * BATCH;
        }
        const float* p = xT + (rg << 5) * BATCH + b0;  // this lane's K-quarter panel

        float4 acc[16];
#pragma unroll
        for (int m = 0; m < 16; ++m) acc[m] = make_float4(0.f, 0.f, 0.f, 0.f);

        float4 xa[8], xb[8];
        IssueQ<0, 8>::go(xa, p);                       // k 0..7 of this lane in flight

#define RING_GRP(G, CUR, NXT, WN, DO_ISSUE)                                   \
        do {                                                                  \
          if (DO_ISSUE) IssueQ<0, 8>::go(NXT, p + ((G) + 1) * 8 * BATCH);     \
          WAIT_VM(WN);                                                        \
          _Pragma("unroll")                                                   \
          for (int cc = 0; cc < 2; ++cc) {                                    \
            _Pragma("unroll")                                                 \
            for (int m = 0; m < 16; ++m) {                                    \
              float4 wq = *(const float4*)(wb_ring + ((G) * 2 + cc) * 256 + toff[m]); \
              AXPY4(acc[m], wq.x, (CUR)[cc * 4 + 0]);                         \
              AXPY4(acc[m], wq.y, (CUR)[cc * 4 + 1]);                         \
              AXPY4(acc[m], wq.z, (CUR)[cc * 4 + 2]);                         \
              AXPY4(acc[m], wq.w, (CUR)[cc * 4 + 3]);                         \
            }                                                                 \
          }                                                                   \
        } while (0)

        RING_GRP(0, xa, xb, 8, true);
        RING_GRP(1, xb, xa, 8, true);
        RING_GRP(2, xa, xb, 8, true);
        RING_GRP(3, xb, xa, 0, false);
#undef RING_GRP

        // pre-reduce the 4 K-quarters across the quad (DPP butterfly), then
        // lane rg==0 writes the full 16-row partial: part[kh][m][b0..b0+3].
#pragma unroll
        for (int m = 0; m < 16; ++m) {
          acc[m].x = qsum(acc[m].x);
          acc[m].y = qsum(acc[m].y);
          acc[m].z = qsum(acc[m].z);
          acc[m].w = qsum(acc[m].w);
        }
        if (rg == 0) {
#pragma unroll
          for (int m = 0; m < 16; ++m)
            *(float4*)(part + (kh << 10) + (m << 6) + b0) = acc[m];
        }
      }
    }

    __syncthreads();  // partials visible

    if (active && tid < 256) {
      float g4[4];
#pragma unroll
      for (int q = 0; q < 4; ++q) {
        float a = bias4[q];
        const int base = (((q << 2) + p_jj) << 6) + p_b;
#pragma unroll
        for (int kk = 0; kk < 8; ++kk) a += part[(kk << 10) + base];
        g4[q] = a;
      }
      float ig = sigm(g4[0]), fg = sigm(g4[1]), gg = tanh_fast(g4[2]), og = sigm(g4[3]);
      c = fmaf(fg, c, ig * gg);
      float h = og * tanh_fast(c);
      float* ring = (layer == 0 ? h0ring : h1ring) + (s & 1) * RING_SLOT;
      cstore(ring + p_jg * BATCH + p_b, h);   // coherent store [j][b], coalesced
      if (layer == 1) {
        const int t = s - 1;
        if (t == slen - 1) out[p_b * HID + p_jg] = h;
      }
    }

    // ---- hierarchical arrive, FLAT release, all-RELAXED, monotonic ----
    // __syncthreads() drains vmcnt(0): every coherent h-store is committed at
    // the IF coherence point before tid0's arrival increment. Consumers read
    // ring data with coherent (sc0 sc1) loads after observing the release.
    __syncthreads();
    if (tid == 0) {
      const int target = s + 1;
      int* leafp = &bar->leaf[(wg >> 4) * 32];
      int prev = __hip_atomic_fetch_add(leafp, 1, __ATOMIC_RELAXED, __HIP_MEMORY_SCOPE_AGENT);
      bool winner = false;
      if ((prev & 15) == 15) {   // 16th arrival of this slot in this group
        int r = __hip_atomic_fetch_add(&bar->root, 1, __ATOMIC_RELAXED, __HIP_MEMORY_SCOPE_AGENT);
        if ((r & 15) == 15) {    // 16th group — release everyone
          __hip_atomic_store(&bar->epoch, target, __ATOMIC_RELAXED, __HIP_MEMORY_SCOPE_AGENT);
          winner = true;
        }
      }
      if (!winner) {
        while (__hip_atomic_load(&bar->epoch, __ATOMIC_RELAXED, __HIP_MEMORY_SCOPE_AGENT) < target)
          __builtin_amdgcn_s_sleep(1);
      }
    }
    __syncthreads();
  }
}

extern "C" void kernel_launch(void* const* d_in, const int* in_sizes, int n_in,
                              void* d_out, int out_size, void* d_ws, size_t ws_size,
                              hipStream_t stream) {
  const int*   src  = (const int*)d_in[0];
  const int*   slen = (const int*)d_in[1];
  const float* emb  = (const float*)d_in[2];
  const float* Wih0 = (const float*)d_in[3];
  const float* Whh0 = (const float*)d_in[4];
  const float* bih0 = (const float*)d_in[5];
  const float* bhh0 = (const float*)d_in[6];
  const float* Wih1 = (const float*)d_in[7];
  const float* Whh1 = (const float*)d_in[8];
  const float* bih1 = (const float*)d_in[9];
  const float* bhh1 = (const float*)d_in[10];
  float* out = (float*)d_out;

  int*   bar    = (int*)d_ws;
  float* h0ring = (float*)((char*)d_ws + 8192);
  float* h1ring = h0ring + 2 * RING_SLOT;

  // zero barrier state + all 4 ring slots (ws is poisoned 0xAA before every launch)
  int zero_ints = (8192 + 4 * RING_SLOT * 4) / 4;
  hipLaunchKernelGGL(init_ws_kernel, dim3(64), dim3(256), 0, stream, (int*)d_ws, zero_ints);

  (void)hipFuncSetAttribute((const void*)lstm_pipe,
                            hipFuncAttributeMaxDynamicSharedMemorySize, 98304);

  hipLaunchKernelGGL(lstm_pipe, dim3(NWG), dim3(TPB), 98304, stream,
                     src, slen, emb, Wih0, Whh0, bih0, bhh0, Wih1, Whh1, bih1, bhh1,
                     out, bar, h0ring, h1ring);
}

// Round 8
// 11440.773 us; speedup vs baseline: 1.3596x; 1.3537x over previous
//
#include <hip/hip_runtime.h>

#define T_LEN 512
#define BATCH 64
#define HID   512
#define EMB   512
#define NWG   256
#define TPB   512
#define RING_SLOT (HID * BATCH)   // 32768 floats per slot, layout [j][b]

// ---- grid barrier state (lives in d_ws, zeroed by init kernel) ----
// Monotonic counters (never reset): leaf[g] gets 16 incs/slot, root gets 16.
// Release: root winner stores epoch; EVERYONE ELSE polls epoch directly.
// (Flat release verified passing in rounds 2-4.)
struct GBar {
  int leaf[16 * 32];   // arrival counter per group, one cacheline apart
  int root; int pad1[31];
  int epoch; int pad2[31];
  int gep[16 * 32];    // unused; kept so ws layout/zeroing is unchanged
};

__global__ void init_ws_kernel(int* ws, int n) {
  int stride = gridDim.x * blockDim.x;
  for (int i = blockIdx.x * blockDim.x + threadIdx.x; i < n; i += stride) ws[i] = 0;
}

__device__ __forceinline__ float sigm(float x)      { return 1.f / (1.f + __expf(-x)); }
// saturation-safe tanh: x->+inf => 1, x->-inf => -1, no inf/inf NaN
__device__ __forceinline__ float tanh_fast(float x) { return 1.f - 2.f / (__expf(2.f * x) + 1.f); }

// coherent (device-scope, cache-bypassing) scalar store — no fences needed
__device__ __forceinline__ void cstore(float* p, float v) {
  __hip_atomic_store(p, v, __ATOMIC_RELAXED, __HIP_MEMORY_SCOPE_AGENT);
}

// LOAD MECHANISM NOTE (rounds 5-7 post-mortem): the hand-rolled fire-and-
// forget asm global_load + counted s_waitcnt pipeline raced whenever the
// compiler emitted ANY read of an asm-load destination register between
// issue and wait (stack temp of an "=v"(arr[i]) operand, or a spill store)
// — no VMEM scoreboard on CDNA, so such reads are garbage. Rounds 2-4
// "passed" only because their spill-heavy schedules accidentally fenced
// everything. Fix: coherent loads the COMPILER can see. __hip_atomic_load
// (relaxed, agent) emits global_load_dwordx2 sc0 sc1 (same L1/L2 bypass as
// the old asm) and the backend waitcnt pass tracks the def natively — every
// use is correctly fenced regardless of scheduling or spilling.
__device__ __forceinline__ float2 cload2(const float* p) {
  unsigned long long u = __hip_atomic_load((const unsigned long long*)p,
                                           __ATOMIC_RELAXED, __HIP_MEMORY_SCOPE_AGENT);
  return __builtin_bit_cast(float2, u);
}

// butterfly sum across the 4 lanes of a quad (rg = lane&3) via DPP quad_perm.
// 0xB1 = quad_perm:[1,0,3,2] (xor 1), 0x4E = quad_perm:[2,3,0,1] (xor 2).
// All lanes end with the full 4-lane sum; stays on the VALU pipe (no LDS).
__device__ __forceinline__ float qsum(float v) {
  int t = __builtin_amdgcn_update_dpp(0, __float_as_int(v), 0xB1, 0xF, 0xF, false);
  v += __int_as_float(t);
  t = __builtin_amdgcn_update_dpp(0, __float_as_int(v), 0x4E, 0xF, 0xF, false);
  v += __int_as_float(t);
  return v;
}

// acc (scalar) += dot(xv, wv)
#define DOT_ACC(a, xv, wv) \
  a = fmaf((xv).w, (wv).w, fmaf((xv).z, (wv).z, fmaf((xv).y, (wv).y, fmaf((xv).x, (wv).x, (a)))))

// REGISTER BUDGET NOTE (rounds 2-5): HIP's two-arg __launch_bounds__(TPB, n)
// itself emits "amdgpu-waves-per-eu"="n" (min only) and overrides a separate
// waves attribute; the backend heuristic then targets 4 waves/EU => 128-VGPR
// budget. One-arg __launch_bounds__ + amdgpu_waves_per_eu(2,2) pins the
// target to what the 96 KB LDS forces anyway (1 block/CU = 2 waves/EU) =>
// 256-VGPR budget. With compiler-visible loads, any residual spill is merely
// slow, never incorrect.
__global__ __launch_bounds__(TPB) __attribute__((amdgpu_waves_per_eu(2, 2)))
void lstm_pipe(
    const int* __restrict__ src, const int* __restrict__ sen_len,
    const float* __restrict__ emb,
    const float* __restrict__ Wih0, const float* __restrict__ Whh0,
    const float* __restrict__ bih0, const float* __restrict__ bhh0,
    const float* __restrict__ Wih1, const float* __restrict__ Whh1,
    const float* __restrict__ bih1, const float* __restrict__ bhh1,
    float* __restrict__ out,
    int* __restrict__ barp, float* __restrict__ h0ring, float* __restrict__ h1ring)
{
  extern __shared__ char smem_raw[];
  float4* WlV  = (float4*)smem_raw;            // 4096 float4 = 64 KB: [kc][16 slots]
  float*  part = (float*)(smem_raw + 65536);   // 8192 floats = 32 KB: [kh][row][b]
  GBar* bar = (GBar*)barp;

  const int wg    = blockIdx.x;
  const int layer = wg >> 7;    // 0: WGs 0..127 (layer0 @ t=s), 1: WGs 128..255 (layer1 @ t=s-1)
  const int w     = wg & 127;   // owns hidden units j in [4w, 4w+4)
  const int tid   = threadIdx.x;
  const int kh    = tid >> 6;   // 0..7  K-segment of 128
  const int lane  = tid & 63;
  const int bg    = lane >> 2;  // 0..15 batch-group (4 batches)
  const int rg    = lane & 3;   // 0..3  ring: K-quarter of 32 | emb: j within WG
  const int b0    = bg << 2;    // batches b0..b0+3 (contiguous)
  const int k0    = kh << 7;    // K range [k0, k0+128)

  const float* Wih = layer ? Wih1 : Wih0;
  const float* Whh = layer ? Whh1 : Whh0;

  // Stage 16 rows x 1024 K of fused [Wih | Whh] weights into LDS, [kc][16] float4.
  // Row-slot swizzle: slot = (rowl + 2*((kc>>3)&3)) & 15.  In ring mode the 4
  // rg lanes read kc's 8 apart ((kc>>3)&3 == rg) => banks spread 0/8/16/24;
  // in emb mode rg is consecutive in the slot => 4 adjacent 16B slots. Both
  // conflict-free; bijective per kc. (Verified passing, rounds 2-4.)
  for (int idx = tid; idx < 4096; idx += TPB) {
    int rowl = idx & 15;          // q*4 + rjj
    int kc   = idx >> 4;          // 0..255
    int q = rowl >> 2, rjj = rowl & 3;
    int grow = q * HID + (w << 2) + rjj;   // global gate row
    int k4 = kc << 2;
    float4 v;
    if (k4 < EMB) v = *(const float4*)(Wih + (size_t)grow * EMB + k4);
    else          v = *(const float4*)(Whh + (size_t)grow * HID + (k4 - EMB));
    int slot = (rowl + 2 * ((kc >> 3) & 3)) & 15;
    WlV[kc * 16 + slot] = v;
  }

  // Per-thread swizzled weight byte-offset table (loop-invariant over all
  // steps; statically indexed everywhere -> stays in VGPRs).
  const bool embmode = (layer == 0) && (kh < 4);
  int toff[16];
  {
    const int add = embmode ? rg : (rg << 1);
#pragma unroll
    for (int i = 0; i < 16; ++i) toff[i] = ((i + add) & 15) << 4;
  }
  const char* wb_ring = (const char*)smem_raw + (size_t)((kh << 5) + (rg << 3)) * 256; // kc_base*256
  const char* wb_emb  = (const char*)smem_raw + (size_t)(kh << 13);                    // kh*8192

  // Activation-phase identity: threads 0..255 own cell (jj, b); c lives here.
  const int p_b  = tid & 63;
  const int p_jj = (tid >> 6) & 3;
  const int p_jg = (w << 2) + p_jj;
  float bias4[4] = {0.f, 0.f, 0.f, 0.f};
  float c = 0.f;
  int   slen = -2;
  if (tid < 256) {
#pragma unroll
    for (int q = 0; q < 4; ++q) {
      int r = q * HID + p_jg;
      bias4[q] = layer ? (bih1[r] + bhh1[r]) : (bih0[r] + bhh0[r]);
    }
    slen = sen_len[p_b];
  }
  __syncthreads();

  for (int s = 0; s <= T_LEN; ++s) {
    const bool active = (layer == 0) ? (s < T_LEN) : (s >= 1);
    if (active) {
      const int t = (layer == 0) ? s : (s - 1);

      if (embmode) {
        // ---- embedding-gather mode: read-only data, normal cached loads ----
        float4 acc[4];
#pragma unroll
        for (int q = 0; q < 4; ++q) acc[q] = make_float4(0.f, 0.f, 0.f, 0.f);
        const int* st = src + t * BATCH + b0;
        const float* e0 = emb + (size_t)st[0] * EMB;
        const float* e1 = emb + (size_t)st[1] * EMB;
        const float* e2 = emb + (size_t)st[2] * EMB;
        const float* e3 = emb + (size_t)st[3] * EMB;
#pragma unroll
        for (int kk = 0; kk < 128; kk += 4) {
          const int sw = (kk >> 5) & 3;           // compile-time (full unroll)
          const int k  = k0 + kk;
          float4 x0 = *(const float4*)(e0 + k);
          float4 x1 = *(const float4*)(e1 + k);
          float4 x2 = *(const float4*)(e2 + k);
          float4 x3 = *(const float4*)(e3 + k);
#pragma unroll
          for (int q = 0; q < 4; ++q) {
            float4 wq = *(const float4*)(wb_emb + kk * 64 + toff[((q << 2) + 2 * sw) & 15]);
            DOT_ACC(acc[q].x, x0, wq);
            DOT_ACC(acc[q].y, x1, wq);
            DOT_ACC(acc[q].z, x2, wq);
            DOT_ACC(acc[q].w, x3, wq);
          }
        }
        // partials: part[kh][row][b], row = q*4+rg
#pragma unroll
        for (int q = 0; q < 4; ++q)
          *(float4*)(part + (kh << 10) + (((q << 2) + rg) << 6) + b0) = acc[q];
      } else {
        // ---- transposed-ring mode: each quad lane owns a disjoint K-quarter
        // of 32 k's (8 kc) and accumulates ALL 16 gate-rows for its 4
        // batches. 64 coherent b64 loads/thread, all compiler-visible
        // (cload2), so waitcnt correctness is the backend's job. Full unroll
        // gives the scheduler freedom to hoist loads across the body.
        const float* xT;
        if (layer == 0) {
          xT = h0ring + ((s + 1) & 1) * RING_SLOT + (k0 - EMB) * BATCH;
        } else if (kh < 4) {
          xT = h0ring + ((s - 1) & 1) * RING_SLOT + k0 * BATCH;
        } else {
          xT = h1ring + ((s - 1) & 1) * RING_SLOT + (k0 - EMB) * BATCH;
        }
        const float* p = xT + (rg << 5) * BATCH + b0;  // this lane's K-quarter panel

        float4 acc[16];
#pragma unroll
        for (int m = 0; m < 16; ++m) acc[m] = make_float4(0.f, 0.f, 0.f, 0.f);

#pragma unroll
        for (int g = 0; g < 8; ++g) {          // g = kc within this lane's quarter
          float2 xv[4][2];                     // [kk][pair]: batches (b0+2pr, b0+2pr+1)
#pragma unroll
          for (int kk = 0; kk < 4; ++kk) {
            const float* rowp = p + (g * 4 + kk) * BATCH;
            xv[kk][0] = cload2(rowp);
            xv[kk][1] = cload2(rowp + 2);
          }
#pragma unroll
          for (int m = 0; m < 16; ++m) {
            float4 wq = *(const float4*)(wb_ring + g * 256 + toff[m]);
            acc[m].x = fmaf(wq.w, xv[3][0].x, fmaf(wq.z, xv[2][0].x,
                       fmaf(wq.y, xv[1][0].x, fmaf(wq.x, xv[0][0].x, acc[m].x))));
            acc[m].y = fmaf(wq.w, xv[3][0].y, fmaf(wq.z, xv[2][0].y,
                       fmaf(wq.y, xv[1][0].y, fmaf(wq.x, xv[0][0].y, acc[m].y))));
            acc[m].z = fmaf(wq.w, xv[3][1].x, fmaf(wq.z, xv[2][1].x,
                       fmaf(wq.y, xv[1][1].x, fmaf(wq.x, xv[0][1].x, acc[m].z))));
            acc[m].w = fmaf(wq.w, xv[3][1].y, fmaf(wq.z, xv[2][1].y,
                       fmaf(wq.y, xv[1][1].y, fmaf(wq.x, xv[0][1].y, acc[m].w))));
          }
        }

        // pre-reduce the 4 K-quarters across the quad (DPP butterfly), then
        // lane rg==0 writes the full 16-row partial: part[kh][m][b0..b0+3].
#pragma unroll
        for (int m = 0; m < 16; ++m) {
          acc[m].x = qsum(acc[m].x);
          acc[m].y = qsum(acc[m].y);
          acc[m].z = qsum(acc[m].z);
          acc[m].w = qsum(acc[m].w);
        }
        if (rg == 0) {
#pragma unroll
          for (int m = 0; m < 16; ++m)
            *(float4*)(part + (kh << 10) + (m << 6) + b0) = acc[m];
        }
      }
    }

    __syncthreads();  // partials visible

    if (active && tid < 256) {
      float g4[4];
#pragma unroll
      for (int q = 0; q < 4; ++q) {
        float a = bias4[q];
        const int base = (((q << 2) + p_jj) << 6) + p_b;
#pragma unroll
        for (int kk = 0; kk < 8; ++kk) a += part[(kk << 10) + base];
        g4[q] = a;
      }
      float ig = sigm(g4[0]), fg = sigm(g4[1]), gg = tanh_fast(g4[2]), og = sigm(g4[3]);
      c = fmaf(fg, c, ig * gg);
      float h = og * tanh_fast(c);
      float* ring = (layer == 0 ? h0ring : h1ring) + (s & 1) * RING_SLOT;
      cstore(ring + p_jg * BATCH + p_b, h);   // coherent store [j][b], coalesced
      if (layer == 1) {
        const int t = s - 1;
        if (t == slen - 1) out[p_b * HID + p_jg] = h;
      }
    }

    // ---- hierarchical arrive, FLAT release, all-RELAXED, monotonic ----
    // __syncthreads() drains vmcnt(0): every coherent h-store is committed at
    // the coherence point before tid0's arrival increment. Consumers read
    // ring data with coherent (sc0 sc1) loads after observing the release.
    __syncthreads();
    if (tid == 0) {
      const int target = s + 1;
      int* leafp = &bar->leaf[(wg >> 4) * 32];
      int prev = __hip_atomic_fetch_add(leafp, 1, __ATOMIC_RELAXED, __HIP_MEMORY_SCOPE_AGENT);
      bool winner = false;
      if ((prev & 15) == 15) {   // 16th arrival of this slot in this group
        int r = __hip_atomic_fetch_add(&bar->root, 1, __ATOMIC_RELAXED, __HIP_MEMORY_SCOPE_AGENT);
        if ((r & 15) == 15) {    // 16th group — release everyone
          __hip_atomic_store(&bar->epoch, target, __ATOMIC_RELAXED, __HIP_MEMORY_SCOPE_AGENT);
          winner = true;
        }
      }
      if (!winner) {
        while (__hip_atomic_load(&bar->epoch, __ATOMIC_RELAXED, __HIP_MEMORY_SCOPE_AGENT) < target)
          __builtin_amdgcn_s_sleep(1);
      }
    }
    __syncthreads();
  }
}

extern "C" void kernel_launch(void* const* d_in, const int* in_sizes, int n_in,
                              void* d_out, int out_size, void* d_ws, size_t ws_size,
                              hipStream_t stream) {
  const int*   src  = (const int*)d_in[0];
  const int*   slen = (const int*)d_in[1];
  const float* emb  = (const float*)d_in[2];
  const float* Wih0 = (const float*)d_in[3];
  const float* Whh0 = (const float*)d_in[4];
  const float* bih0 = (const float*)d_in[5];
  const float* bhh0 = (const float*)d_in[6];
  const float* Wih1 = (const float*)d_in[7];
  const float* Whh1 = (const float*)d_in[8];
  const float* bih1 = (const float*)d_in[9];
  const float* bhh1 = (const float*)d_in[10];
  float* out = (float*)d_out;

  int*   bar    = (int*)d_ws;
  float* h0ring = (float*)((char*)d_ws + 8192);
  float* h1ring = h0ring + 2 * RING_SLOT;

  // zero barrier state + all 4 ring slots (ws is poisoned 0xAA before every launch)
  int zero_ints = (8192 + 4 * RING_SLOT * 4) / 4;
  hipLaunchKernelGGL(init_ws_kernel, dim3(64), dim3(256), 0, stream, (int*)d_ws, zero_ints);

  (void)hipFuncSetAttribute((const void*)lstm_pipe,
                            hipFuncAttributeMaxDynamicSharedMemorySize, 98304);

  hipLaunchKernelGGL(lstm_pipe, dim3(NWG), dim3(TPB), 98304, stream,
                     src, slen, emb, Wih0, Whh0, bih0, bhh0, Wih1, Whh1, bih1, bhh1,
                     out, bar, h0ring, h1ring);
}